// Round 1
// baseline (963.849 us; speedup 1.0000x reference)
//
#include <hip/hip_runtime.h>
#include <hip/hip_bf16.h>
#include <math.h>

#define T_TOKENS 8192
#define DDIM 1024
#define HDIM 4096
#define NEXP 8
#define CAP 8192      // max tokens per expert
#define MAXTILES 72   // sum_e ceil(cnt_e/256) <= 64 + 8 = 72; 72 % 8 == 0 (XCD math)

typedef __bf16 bf16;
typedef __bf16 bf16x4 __attribute__((ext_vector_type(4)));
typedef __bf16 bf16x8 __attribute__((ext_vector_type(8)));
typedef float  floatx4 __attribute__((ext_vector_type(4)));

// async global->LDS, 16 bytes per lane; LDS dest = wave-uniform base + lane*16.
__device__ static inline void async_load16(const void* g, void* l)
{
    __builtin_amdgcn_global_load_lds(
        (const __attribute__((address_space(1))) void*)g,
        (__attribute__((address_space(3))) void*)l, 16, 0, 0);
}

// ---------------------------------------------------------------------------
// Kernel 1: router. 4 waves/block, one token per wave. fp32 logits (exact;
// selection matches jax.lax.top_k incl. lowest-index tie-break).
// ---------------------------------------------------------------------------
__global__ void router_kernel(const float* __restrict__ x,
                              const float* __restrict__ gw,
                              const float* __restrict__ gbias,
                              float* __restrict__ logits_out,
                              int* counts, int* token_of,
                              int* selpack, int* slots, float* wts)
{
    int t = blockIdx.x * 4 + (threadIdx.x >> 6);
    int l = threadIdx.x & 63;
    const float4* xr = (const float4*)(x + (size_t)t * DDIM);

    float p[NEXP];
#pragma unroll
    for (int e = 0; e < NEXP; ++e) p[e] = 0.f;

#pragma unroll
    for (int it = 0; it < 4; ++it) {
        int d4 = it * 64 + l;
        float4 v = xr[d4];
        float vv[4] = {v.x, v.y, v.z, v.w};
#pragma unroll
        for (int j = 0; j < 4; ++j) {
            const float4* g4 = (const float4*)(gw + (size_t)(d4 * 4 + j) * NEXP);
            float4 ga = g4[0], gb4 = g4[1];
            p[0] += vv[j] * ga.x;  p[1] += vv[j] * ga.y;
            p[2] += vv[j] * ga.z;  p[3] += vv[j] * ga.w;
            p[4] += vv[j] * gb4.x; p[5] += vv[j] * gb4.y;
            p[6] += vv[j] * gb4.z; p[7] += vv[j] * gb4.w;
        }
    }
#pragma unroll
    for (int e = 0; e < NEXP; ++e) {
#pragma unroll
        for (int off = 32; off; off >>= 1) p[e] += __shfl_xor(p[e], off);
        p[e] += gbias[e];
    }
    if (l < NEXP) logits_out[(size_t)t * NEXP + l] = p[l];

    if (l == 0) {
        int e0 = 0;
#pragma unroll
        for (int e = 1; e < NEXP; ++e) if (p[e] > p[e0]) e0 = e;
        int e1 = -1;
#pragma unroll
        for (int e = 0; e < NEXP; ++e) {
            if (e == e0) continue;
            if (e1 < 0 || p[e] > p[e1]) e1 = e;
        }
        float w0 = 1.f / (1.f + expf(p[e1] - p[e0]));
        float w1 = 1.f / (1.f + expf(p[e0] - p[e1]));
        int s0 = atomicAdd(&counts[e0], 1);
        int s1 = atomicAdd(&counts[e1], 1);
        token_of[e0 * CAP + s0] = t;
        token_of[e1 * CAP + s1] = t;
        selpack[t] = e0 | (e1 << 8);
        slots[2 * t]     = s0;
        slots[2 * t + 1] = s1;
        wts[2 * t]     = w0;
        wts[2 * t + 1] = w1;
    }
}

// ---------------------------------------------------------------------------
// Kernel 2: offsets + XCD-transposed 256-row tile list. Lane-parallel, no
// scratch arrays (old version: 1 thread + runtime-indexed local array ->
// scratch memory, serial latency chain). tiles[p] for p = c + 8*k carries
// ordered-tile c*per+k so a contiguous (~one expert) run of tiles lands on
// one XCD (grid.x == 72 == 0 mod 8). [R4-verified technique]
// ---------------------------------------------------------------------------
__global__ void offsets_kernel(const int* __restrict__ counts,
                               int* __restrict__ offsets,
                               int* __restrict__ tiles)
{
    __shared__ int off[NEXP + 1], tstart[NEXP + 1];
    int t = threadIdx.x;
    if (t == 0) {
        int a = 0, nt = 0;
        for (int e = 0; e < NEXP; ++e) {
            off[e] = a; tstart[e] = nt;
            int c = counts[e];
            a += c; nt += (c + 255) >> 8;
        }
        off[NEXP] = a;        // == 2*T_TOKENS
        tstart[NEXP] = nt;
    }
    __syncthreads();
    if (t <= NEXP) offsets[t] = off[t];
    int nt = tstart[NEXP];
    int per = (nt + 7) >> 3;
    if (t < MAXTILES) {
        int c = t & 7, k = t >> 3;
        int src = c * per + k;
        int v = -1;
        if (k < per && src < nt) {
            int e = 0;
#pragma unroll
            for (int i = 1; i < NEXP; ++i) e += (src >= tstart[i]);
            v = (e << 24) | (off[e] + (src - tstart[e]) * 256);
        }
        tiles[t] = v;
    }
}

// ---------------------------------------------------------------------------
// Kernel 3: gather over compact rows. 4 waves/block, one row per wave.
// ---------------------------------------------------------------------------
__global__ void gather_kernel(const float* __restrict__ x,
                              const int* __restrict__ offsets,
                              const int* __restrict__ token_of,
                              bf16* __restrict__ xg)
{
    int row = blockIdx.x * 4 + (threadIdx.x >> 6);
    int l = threadIdx.x & 63;
    int e = 0;
#pragma unroll
    for (int i = 1; i < NEXP; ++i) e += (row >= offsets[i]);
    int t = token_of[e * CAP + (row - offsets[e])];
    const float4* src = (const float4*)(x + (size_t)t * DDIM);
    bf16x4* dst = (bf16x4*)(xg + (size_t)row * DDIM);
#pragma unroll
    for (int it = 0; it < 4; ++it) {
        float4 v = src[it * 64 + l];
        bf16x4 b;
        b[0] = (bf16)v.x; b[1] = (bf16)v.y; b[2] = (bf16)v.z; b[3] = (bf16)v.w;
        dst[it * 64 + l] = b;
    }
}

// ---------------------------------------------------------------------------
// Kernel 4: both weight transposes in ONE launch (fp32 [E][R][C] -> bf16
// [E][C][R]).  blocks 0..8191: w1 (R=1024,C=4096); 8192..16383: w2 (swap).
// 64x64 tile, 256 threads, 16 B/lane both directions.
// ---------------------------------------------------------------------------
__global__ void transpose_cvt_kernel(const float* __restrict__ w1,
                                     const float* __restrict__ w2,
                                     bf16* __restrict__ w1b,
                                     bf16* __restrict__ w2b)
{
    __shared__ bf16 tile[64][68];
    int b = blockIdx.x;
    int R, C, e, tr, tc;
    const float* src;
    bf16* dst;
    if (b < 8192) {
        R = DDIM; C = HDIM;
        e = b >> 10; int tt = b & 1023;        // 1024 tiles: 64(c) x 16(r)
        tc = tt & 63; tr = tt >> 6;
        src = w1 + (size_t)e * R * C; dst = w1b + (size_t)e * R * C;
    } else {
        b -= 8192;
        R = HDIM; C = DDIM;
        e = b >> 10; int tt = b & 1023;        // 1024 tiles: 16(c) x 64(r)
        tc = tt & 15; tr = tt >> 4;
        src = w2 + (size_t)e * R * C; dst = w2b + (size_t)e * R * C;
    }
    int r0 = tr * 64, c0 = tc * 64;
    int t = threadIdx.x;
    int lr = t >> 4, c4 = t & 15;
#pragma unroll
    for (int it = 0; it < 4; ++it) {
        int r = lr + it * 16;
        float4 v = *(const float4*)(src + (size_t)(r0 + r) * C + c0 + c4 * 4);
        bf16x4 bb;
        bb[0] = (bf16)v.x; bb[1] = (bf16)v.y; bb[2] = (bf16)v.z; bb[3] = (bf16)v.w;
        *(bf16x4*)(&tile[r][c4 * 4]) = bb;
    }
    __syncthreads();
    int oc = t >> 3, rseg = (t & 7) * 8;
#pragma unroll
    for (int it = 0; it < 2; ++it) {
        int c = oc + it * 32;
        bf16x8 v;
#pragma unroll
        for (int j = 0; j < 8; ++j) v[j] = tile[rseg + j][c];
        *(bf16x8*)(dst + (size_t)(c0 + c) * R + r0 + rseg) = v;
    }
}

__device__ static inline float fast_gelu(float v)
{
    float z = v * (2.302236479f + 0.1029451170f * v * v);
    float ex = __builtin_amdgcn_exp2f(z);
    return v * ex * __builtin_amdgcn_rcpf(ex + 1.f);
}

// ---------------------------------------------------------------------------
// MFMA GEMM, 8-phase-style schedule (T3+T4+T5): 256x256 tile, BK=32,
// 4-deep LDS ring (128 KB), stage K-tile t+3 while computing t, boundary
// wait = s_waitcnt vmcnt(8) (never 0 -> 8 loads always in flight), raw
// s_barrier (no drain), setprio(1) around each 16-MFMA cluster.
//   deadline proof: at iter t's vmcnt(8): issued = 12 + 4(t+1); wait leaves
//   <=8 outstanding -> >=4t+8 complete = tiles 0..t+1 fully staged.
//   WAR: iter t stages buf[(t+3)&3] == buf[(t-1)&3]; its readers' ds_reads
//   complete before iter t-1's closing barrier (consumers pinned by
//   sched_barrier), staging issues after it.
// LDS swizzle: row r (64 B = 4 chunks of 16 B) stores logical chunk c at
// phys c ^ ((r>>1)&3)  -> reads are 2-way max (free, m136). Achieved by
// pre-swizzling the *global* source (linear LDS dest, G21).
// A: [rows,KTOT] bf16. B: [E][NTOT][KTOT] bf16. 8 waves = 2(M) x 4(N),
// wave tile 128x64 = acc[8][4] x floatx4.
// ---------------------------------------------------------------------------
template<int KTOT, int NTOT, bool DOGELU, typename OutT>
__global__ __launch_bounds__(512, 2)
void moe_gemm(const bf16* __restrict__ Abase, const bf16* __restrict__ Bbase,
              const float* __restrict__ bias, OutT* __restrict__ Out,
              const int* __restrict__ tiles, const int* __restrict__ offsets)
{
    constexpr int NK = KTOT / 32;
    __shared__ __align__(16) bf16 lds[4 * 2 * 256 * 32];   // 128 KB, 4 bufs

    int info = tiles[blockIdx.x];
    if (info < 0) return;
    int e = info >> 24, row0 = info & 0xffffff;
    int valid = offsets[e + 1] - row0; if (valid > 256) valid = 256;
    int n0 = blockIdx.y * 256;

    const bf16* A = Abase + (size_t)row0 * KTOT;
    const bf16* B = Bbase + (size_t)e * NTOT * KTOT + (size_t)n0 * KTOT;
    const float* bvec = bias + (size_t)e * NTOT + n0;

    int tid = threadIdx.x;
    int lane = tid & 63, wave = tid >> 6;      // 8 waves
    int wm = wave >> 2, wn = wave & 3;         // 2(M) x 4(N)
    int m16 = lane & 15, quad = lane >> 4;
    int pcb = (quad ^ ((m16 >> 1) & 3)) * 8;   // read-side phys chunk (bf16 idx)

    // staging lane decomposition: 64 lanes x 16 B = 16 rows x 4 chunks
    int rowoff = lane >> 2;                    // 0..15
    int clog = (lane & 3) ^ ((lane >> 3) & 3); // logical chunk for phys lane&3

    int ar0 = wave * 16 + rowoff;              // rows 0..127
    int ar1 = 128 + wave * 16 + rowoff;        // rows 128..255
    const bf16* gA0 = A + (size_t)(ar0 < valid ? ar0 : valid - 1) * KTOT + clog * 8;
    const bf16* gA1 = A + (size_t)(ar1 < valid ? ar1 : valid - 1) * KTOT + clog * 8;
    const bf16* gB0 = B + (size_t)ar0 * KTOT + clog * 8;
    const bf16* gB1 = B + (size_t)ar1 * KTOT + clog * 8;

    int ldsW0 = wave * 16 * 32;                // elements, rows wave*16..
    int ldsW1 = (128 + wave * 16) * 32;

    floatx4 acc[8][4];
#pragma unroll
    for (int m = 0; m < 8; ++m)
#pragma unroll
        for (int n = 0; n < 4; ++n)
#pragma unroll
            for (int r = 0; r < 4; ++r) acc[m][n][r] = 0.f;

    // prologue: stage K-tiles 0,1,2 into ring buffers 0,1,2 (12 loads/wave)
#pragma unroll
    for (int pt = 0; pt < 3; ++pt) {
        bf16* bufA = lds + pt * 16384;
        bf16* bufB = bufA + 8192;
        async_load16(gA0 + pt * 32, bufA + ldsW0);
        async_load16(gA1 + pt * 32, bufA + ldsW1);
        async_load16(gB0 + pt * 32, bufB + ldsW0);
        async_load16(gB1 + pt * 32, bufB + ldsW1);
    }
    asm volatile("s_waitcnt vmcnt(8)" ::: "memory");   // tile 0 resident
    __builtin_amdgcn_s_barrier();
    __builtin_amdgcn_sched_barrier(0);

    for (int t = 0; t < NK; ++t) {
        const bf16* As = lds + (t & 3) * 16384;
        const bf16* Bs = As + 8192;
        int s = t + 3; if (s > NK - 1) s = NK - 1;     // tail: dummy re-stage
        bf16* stA = lds + ((t + 3) & 3) * 16384;       // == buf[(t-1)&3], free
        bf16* stB = stA + 8192;

        // -------- phase 0: ds_read B[0..3]+A[0..3] | stage A half-pair ----
        bf16x8 bfr[4], af[4];
#pragma unroll
        for (int n = 0; n < 4; ++n)
            bfr[n] = *(const bf16x8*)(&Bs[(wn * 64 + n * 16 + m16) * 32 + pcb]);
#pragma unroll
        for (int m = 0; m < 4; ++m)
            af[m] = *(const bf16x8*)(&As[(wm * 128 + m * 16 + m16) * 32 + pcb]);
        async_load16(gA0 + s * 32, stA + ldsW0);
        async_load16(gA1 + s * 32, stA + ldsW1);
        __builtin_amdgcn_s_barrier();
        __builtin_amdgcn_sched_barrier(0);
        __builtin_amdgcn_s_setprio(1);
#pragma unroll
        for (int m = 0; m < 4; ++m)
#pragma unroll
            for (int n = 0; n < 4; ++n)
                acc[m][n] = __builtin_amdgcn_mfma_f32_16x16x32_bf16(
                    af[m], bfr[n], acc[m][n], 0, 0, 0);
        __builtin_amdgcn_s_setprio(0);
        __builtin_amdgcn_s_barrier();
        __builtin_amdgcn_sched_barrier(0);

        // -------- phase 1: ds_read A[4..7] | stage B half-pair | vmcnt(8) --
        bf16x8 ag[4];
#pragma unroll
        for (int m = 0; m < 4; ++m)
            ag[m] = *(const bf16x8*)(&As[(wm * 128 + (m + 4) * 16 + m16) * 32 + pcb]);
        async_load16(gB0 + s * 32, stB + ldsW0);
        async_load16(gB1 + s * 32, stB + ldsW1);
        __builtin_amdgcn_s_barrier();
        __builtin_amdgcn_sched_barrier(0);
        __builtin_amdgcn_s_setprio(1);
#pragma unroll
        for (int m = 0; m < 4; ++m)
#pragma unroll
            for (int n = 0; n < 4; ++n)
                acc[m + 4][n] = __builtin_amdgcn_mfma_f32_16x16x32_bf16(
                    ag[m], bfr[n], acc[m + 4][n], 0, 0, 0);
        __builtin_amdgcn_s_setprio(0);
        asm volatile("s_waitcnt vmcnt(8)" ::: "memory"); // tile t+1 resident
        __builtin_amdgcn_s_barrier();
        __builtin_amdgcn_sched_barrier(0);
    }

    // epilogue: C/D layout col = lane&15, row = quad*4 + reg  [m89-verified]
#pragma unroll
    for (int m = 0; m < 8; ++m) {
#pragma unroll
        for (int r = 0; r < 4; ++r) {
            int lrow = wm * 128 + m * 16 + quad * 4 + r;
            if (lrow >= valid) continue;
            size_t orow = (size_t)(row0 + lrow) * NTOT + n0;
#pragma unroll
            for (int n = 0; n < 4; ++n) {
                int lcol = wn * 64 + n * 16 + m16;
                float v = acc[m][n][r] + bvec[lcol];
                if (DOGELU) v = fast_gelu(v);
                Out[orow + lcol] = (OutT)v;
            }
        }
    }
}

// ---------------------------------------------------------------------------
// Kernel 7: combine. out[t] = w0*y[pos0] + w1*y[pos1].
// ---------------------------------------------------------------------------
__global__ void combine_kernel(const float* __restrict__ y,
                               const int* __restrict__ offsets,
                               const int* __restrict__ selpack,
                               const int* __restrict__ slots,
                               const float* __restrict__ wts,
                               float* __restrict__ out)
{
    int t = blockIdx.x;
    int sp = selpack[t];
    int e0 = sp & 0xff, e1 = (sp >> 8) & 0xff;
    int p0 = offsets[e0] + slots[2 * t];
    int p1 = offsets[e1] + slots[2 * t + 1];
    float w0 = wts[2 * t], w1 = wts[2 * t + 1];
    const float4* y0 = (const float4*)(y + (size_t)p0 * DDIM);
    const float4* y1 = (const float4*)(y + (size_t)p1 * DDIM);
    float4* o = (float4*)(out + (size_t)t * DDIM);
    int tid = threadIdx.x;
    float4 a = y0[tid], b = y1[tid];
    float4 rr;
    rr.x = w0 * a.x + w1 * b.x;
    rr.y = w0 * a.y + w1 * b.y;
    rr.z = w0 * a.z + w1 * b.z;
    rr.w = w0 * a.w + w1 * b.w;
    o[tid] = rr;
}

// ---------------------------------------------------------------------------
extern "C" void kernel_launch(void* const* d_in, const int* in_sizes, int n_in,
                              void* d_out, int out_size, void* d_ws, size_t ws_size,
                              hipStream_t stream)
{
    (void)in_sizes; (void)n_in; (void)out_size; (void)ws_size;
    const float* x  = (const float*)d_in[0];
    const float* gw = (const float*)d_in[1];
    const float* gb = (const float*)d_in[2];
    const float* w1 = (const float*)d_in[3];
    const float* b1 = (const float*)d_in[4];
    const float* w2 = (const float*)d_in[5];
    const float* b2 = (const float*)d_in[6];
    float* out    = (float*)d_out;
    float* logits = out + (size_t)T_TOKENS * DDIM;

    char* ws = (char*)d_ws;
    const size_t MB = 1024 * 1024;
    int*   counts   = (int*)(ws + 0);
    int*   offsets  = (int*)(ws + 256);
    int*   tiles    = (int*)(ws + 512);                  // 72 ints
    int*   selpack  = (int*)(ws + 4096);                 // 32 KB
    int*   slots    = (int*)(ws + 4096 + 32 * 1024);     // 64 KB
    float* wts      = (float*)(ws + 4096 + 96 * 1024);   // 64 KB
    int*   token_of = (int*)(ws + 4096 + 160 * 1024);    // 256 KB
    bf16*  xg  = (bf16*)(ws + 1 * MB);    // 32 MB
    bf16*  w1b = (bf16*)(ws + 33 * MB);   // [E][H][D] 64 MB
    bf16*  w2b = (bf16*)(ws + 97 * MB);   // [E][D][H] 64 MB
    bf16*  mid = (bf16*)(ws + 161 * MB);  // 128 MB
    float* y   = (float*)(ws + 289 * MB); // 64 MB

    hipMemsetAsync(counts, 0, 32, stream);

    router_kernel<<<T_TOKENS / 4, 256, 0, stream>>>(x, gw, gb, logits, counts,
                                                    token_of, selpack, slots, wts);
    offsets_kernel<<<1, 128, 0, stream>>>(counts, offsets, tiles);
    gather_kernel<<<2 * T_TOKENS / 4, 256, 0, stream>>>(x, offsets, token_of, xg);
    transpose_cvt_kernel<<<16384, 256, 0, stream>>>(w1, w2, w1b, w2b);
    // GEMM1: mid = gelu(xg @ w1b[e] + b1[e])
    moe_gemm<DDIM, HDIM, true, bf16><<<dim3(MAXTILES, HDIM / 256), 512, 0, stream>>>(
        xg, w1b, b1, mid, tiles, offsets);
    // GEMM2: y = mid @ w2b[e] + b2[e]
    moe_gemm<HDIM, DDIM, false, float><<<dim3(MAXTILES, DDIM / 256), 512, 0, stream>>>(
        mid, w2b, b2, y, tiles, offsets);
    combine_kernel<<<T_TOKENS, 256, 0, stream>>>(y, offsets, selpack, slots, wts, out);
}